// Round 1
// baseline (730.591 us; speedup 1.0000x reference)
//
#include <hip/hip_runtime.h>
#include <hip/hip_bf16.h>

#define N_NODES_C 50000
#define HIDDEN_C 64
#define NUM_GRAPHS_C 256

// ---------------- scatter-add: one wave per edge, lane = feature ----------------
__global__ __launch_bounds__(256) void k_scatter(const float* __restrict__ x,
                                                 const int* __restrict__ src,
                                                 const int* __restrict__ dst,
                                                 float* __restrict__ h,
                                                 int nE) {
    int wid = (blockIdx.x * 256 + threadIdx.x) >> 6;
    int lane = threadIdx.x & 63;
    int nW = (gridDim.x * 256) >> 6;
    for (int e = wid; e < nE; e += nW) {
        int s = src[e];
        int d = dst[e];
        float v = x[s * 64 + lane];
        atomicAdd(&h[d * 64 + lane], v);
    }
}

// ---------------- fused 2-layer MLP (64x64 each) with ReLU ----------------
// block = 256 threads, tile = 64 nodes. In-place safe (tile read fully before write).
__global__ __launch_bounds__(256) void k_mlp(const float* __restrict__ h_in,
                                             float* __restrict__ h_out,
                                             const float* __restrict__ W1,
                                             const float* __restrict__ b1,
                                             const float* __restrict__ W2,
                                             const float* __restrict__ b2,
                                             int nNodes) {
    __shared__ float sW[64 * 64];
    __shared__ float sH[64 * 65];
    __shared__ float sH1[64 * 65];
    __shared__ float sB[64];

    int tid = threadIdx.x;
    int n0 = blockIdx.x * 64;

    for (int i = tid; i < 4096; i += 256) sW[i] = W1[i];
    if (tid < 64) sB[tid] = b1[tid];
    for (int i = tid; i < 4096; i += 256) {
        int node = i >> 6, f = i & 63;
        float v = (n0 + node < nNodes) ? h_in[(size_t)(n0 + node) * 64 + f] : 0.f;
        sH[node * 65 + f] = v;
    }
    __syncthreads();

    int nr = (tid >> 4) * 4;   // node base (0..60 step 4)
    int fc = (tid & 15) * 4;   // feat base (0..60 step 4)

    float acc[4][4];
#pragma unroll
    for (int i = 0; i < 4; ++i)
#pragma unroll
        for (int j = 0; j < 4; ++j) acc[i][j] = sB[fc + j];

#pragma unroll 8
    for (int k = 0; k < 64; ++k) {
        float a0 = sH[(nr + 0) * 65 + k];
        float a1 = sH[(nr + 1) * 65 + k];
        float a2 = sH[(nr + 2) * 65 + k];
        float a3 = sH[(nr + 3) * 65 + k];
        float w0 = sW[k * 64 + fc + 0];
        float w1 = sW[k * 64 + fc + 1];
        float w2 = sW[k * 64 + fc + 2];
        float w3 = sW[k * 64 + fc + 3];
        acc[0][0] += a0 * w0; acc[0][1] += a0 * w1; acc[0][2] += a0 * w2; acc[0][3] += a0 * w3;
        acc[1][0] += a1 * w0; acc[1][1] += a1 * w1; acc[1][2] += a1 * w2; acc[1][3] += a1 * w3;
        acc[2][0] += a2 * w0; acc[2][1] += a2 * w1; acc[2][2] += a2 * w2; acc[2][3] += a2 * w3;
        acc[3][0] += a3 * w0; acc[3][1] += a3 * w1; acc[3][2] += a3 * w2; acc[3][3] += a3 * w3;
    }

    // relu -> sH1
#pragma unroll
    for (int i = 0; i < 4; ++i)
#pragma unroll
        for (int j = 0; j < 4; ++j)
            sH1[(nr + i) * 65 + fc + j] = fmaxf(acc[i][j], 0.f);

    __syncthreads();  // everyone done reading sW/sB
    for (int i = tid; i < 4096; i += 256) sW[i] = W2[i];
    if (tid < 64) sB[tid] = b2[tid];
    __syncthreads();

#pragma unroll
    for (int i = 0; i < 4; ++i)
#pragma unroll
        for (int j = 0; j < 4; ++j) acc[i][j] = sB[fc + j];

#pragma unroll 8
    for (int k = 0; k < 64; ++k) {
        float a0 = sH1[(nr + 0) * 65 + k];
        float a1 = sH1[(nr + 1) * 65 + k];
        float a2 = sH1[(nr + 2) * 65 + k];
        float a3 = sH1[(nr + 3) * 65 + k];
        float w0 = sW[k * 64 + fc + 0];
        float w1 = sW[k * 64 + fc + 1];
        float w2 = sW[k * 64 + fc + 2];
        float w3 = sW[k * 64 + fc + 3];
        acc[0][0] += a0 * w0; acc[0][1] += a0 * w1; acc[0][2] += a0 * w2; acc[0][3] += a0 * w3;
        acc[1][0] += a1 * w0; acc[1][1] += a1 * w1; acc[1][2] += a1 * w2; acc[1][3] += a1 * w3;
        acc[2][0] += a2 * w0; acc[2][1] += a2 * w1; acc[2][2] += a2 * w2; acc[2][3] += a2 * w3;
        acc[3][0] += a3 * w0; acc[3][1] += a3 * w1; acc[3][2] += a3 * w2; acc[3][3] += a3 * w3;
    }

#pragma unroll
    for (int i = 0; i < 4; ++i) {
        int node = n0 + nr + i;
        if (node < nNodes) {
#pragma unroll
            for (int j = 0; j < 4; ++j)
                h_out[(size_t)node * 64 + fc + j] = fmaxf(acc[i][j], 0.f);
        }
    }
}

// ---------------- per-feature sum & sumsq reduction ----------------
__global__ __launch_bounds__(256) void k_stats(const float* __restrict__ h,
                                               float* __restrict__ stats,
                                               int nNodes) {
    int f = threadIdx.x & 63;
    int rl = threadIdx.x >> 6;  // 0..3
    float s = 0.f, q = 0.f;
    for (int r = blockIdx.x * 4 + rl; r < nNodes; r += gridDim.x * 4) {
        float v = h[(size_t)r * 64 + f];
        s += v;
        q += v * v;
    }
    __shared__ float redS[4][64];
    __shared__ float redQ[4][64];
    redS[rl][f] = s;
    redQ[rl][f] = q;
    __syncthreads();
    if (threadIdx.x < 64) {
        float S = redS[0][threadIdx.x] + redS[1][threadIdx.x] + redS[2][threadIdx.x] + redS[3][threadIdx.x];
        float Q = redQ[0][threadIdx.x] + redQ[1][threadIdx.x] + redQ[2][threadIdx.x] + redQ[3][threadIdx.x];
        atomicAdd(&stats[threadIdx.x], S);
        atomicAdd(&stats[64 + threadIdx.x], Q);
    }
}

// ---------------- BN finalize: scale/shift ----------------
__global__ void k_bnfin(const float* __restrict__ stats,
                        const float* __restrict__ gamma,
                        const float* __restrict__ beta,
                        float* __restrict__ bnp,
                        float invN) {
    int f = threadIdx.x;  // 64 threads
    float mean = stats[f] * invN;
    float var = stats[64 + f] * invN - mean * mean;
    float sc = gamma[f] * rsqrtf(var + 1e-5f);
    bnp[f] = sc;
    bnp[64 + f] = beta[f] - mean * sc;
}

// ---------------- BN apply + ReLU ----------------
__global__ __launch_bounds__(256) void k_bnapply(const float4* __restrict__ h,
                                                 const float* __restrict__ bnp,
                                                 float4* __restrict__ xout,
                                                 int n4) {
    int i = blockIdx.x * 256 + threadIdx.x;
    if (i >= n4) return;
    int fb = (i * 4) & 63;
    float4 v = h[i];
    float s0 = bnp[fb + 0], s1 = bnp[fb + 1], s2 = bnp[fb + 2], s3 = bnp[fb + 3];
    float t0 = bnp[64 + fb + 0], t1 = bnp[64 + fb + 1], t2 = bnp[64 + fb + 2], t3 = bnp[64 + fb + 3];
    float4 r;
    r.x = fmaxf(v.x * s0 + t0, 0.f);
    r.y = fmaxf(v.y * s1 + t1, 0.f);
    r.z = fmaxf(v.z * s2 + t2, 0.f);
    r.w = fmaxf(v.w * s3 + t3, 0.f);
    xout[i] = r;
}

// ---------------- segment-sum pooling + final GEMV (NUM_CLASSES=1) ----------------
__device__ __forceinline__ int lower_bound_dev(const int* a, int n, int key) {
    int lo = 0, hi = n;
    while (lo < hi) {
        int mid = (lo + hi) >> 1;
        if (a[mid] < key) lo = mid + 1; else hi = mid;
    }
    return lo;
}

__global__ __launch_bounds__(256) void k_pool(const float* __restrict__ x,
                                              const int* __restrict__ batch,
                                              const float* __restrict__ Wf,
                                              const float* __restrict__ bf,
                                              float* __restrict__ out,
                                              int nNodes) {
    int g = blockIdx.x;
    int lo = lower_bound_dev(batch, nNodes, g);
    int hi = lower_bound_dev(batch, nNodes, g + 1);
    int f = threadIdx.x & 63;
    int rl = threadIdx.x >> 6;
    float acc = 0.f;
    for (int r = lo + rl; r < hi; r += 4) acc += x[(size_t)r * 64 + f];
    __shared__ float red[4][64];
    red[rl][f] = acc;
    __syncthreads();
    if (threadIdx.x < 64) {
        float s = red[0][threadIdx.x] + red[1][threadIdx.x] + red[2][threadIdx.x] + red[3][threadIdx.x];
        float p = s * Wf[threadIdx.x];
#pragma unroll
        for (int o = 32; o > 0; o >>= 1) p += __shfl_down(p, o, 64);
        if (threadIdx.x == 0) out[g] = p + bf[0];
    }
}

extern "C" void kernel_launch(void* const* d_in, const int* in_sizes, int n_in,
                              void* d_out, int out_size, void* d_ws, size_t ws_size,
                              hipStream_t stream) {
    const float* x_in  = (const float*)d_in[0];
    const int*   ei    = (const int*)d_in[1];
    const int*   batch = (const int*)d_in[2];
    const float* W1    = (const float*)d_in[3];
    const float* b1    = (const float*)d_in[4];
    const float* W2    = (const float*)d_in[5];
    const float* b2    = (const float*)d_in[6];
    const float* gamma = (const float*)d_in[7];
    const float* beta  = (const float*)d_in[8];
    const float* Wf    = (const float*)d_in[9];
    const float* bf    = (const float*)d_in[10];

    const int nNodes = in_sizes[0] / HIDDEN_C;          // 50000
    const int nE = in_sizes[1] / 2;                     // 800000
    const int* src = ei;
    const int* dst = ei + nE;

    const size_t NB = (size_t)nNodes * HIDDEN_C * sizeof(float);  // 12.8 MB
    char* ws = (char*)d_ws;
    float* bufA  = (float*)ws;                 // h work buffer
    float* bufB  = (float*)(ws + NB);          // x ping buffer
    float* stats = (float*)(ws + 2 * NB);      // 128 floats
    float* bnp   = stats + 128;                // 128 floats

    const float* xcur = x_in;
    const int mlpGrid = (nNodes + 63) / 64;
    const int n4 = nNodes * HIDDEN_C / 4;
    const int applyGrid = (n4 + 255) / 256;

    for (int i = 0; i < 3; ++i) {
        hipMemsetAsync(stats, 0, 128 * sizeof(float), stream);
        // h = x  (GIN eps=0: (1+eps)*x + agg)
        hipMemcpyAsync(bufA, xcur, NB, hipMemcpyDeviceToDevice, stream);
        k_scatter<<<2048, 256, 0, stream>>>(xcur, src, dst, bufA, nE);
        k_mlp<<<mlpGrid, 256, 0, stream>>>(bufA, bufA,
                                           W1 + (size_t)i * 4096, b1 + (size_t)i * 64,
                                           W2 + (size_t)i * 4096, b2 + (size_t)i * 64,
                                           nNodes);
        k_stats<<<512, 256, 0, stream>>>(bufA, stats, nNodes);
        k_bnfin<<<1, 64, 0, stream>>>(stats, gamma + (size_t)i * 64, beta + (size_t)i * 64,
                                      bnp, 1.f / (float)nNodes);
        k_bnapply<<<applyGrid, 256, 0, stream>>>((const float4*)bufA, bnp, (float4*)bufB, n4);
        xcur = bufB;
    }

    k_pool<<<NUM_GRAPHS_C, 256, 0, stream>>>(bufB, batch, Wf, bf, (float*)d_out, nNodes);
}

// Round 2
// 526.926 us; speedup vs baseline: 1.3865x; 1.3865x over previous
//
#include <hip/hip_runtime.h>
#include <hip/hip_bf16.h>

#define HIDDEN_C 64
#define NUM_GRAPHS_C 256

// ---------------- CSR build ----------------
__global__ __launch_bounds__(256) void k_hist(const int* __restrict__ dst,
                                              int* __restrict__ deg, int nE) {
    int i = blockIdx.x * 256 + threadIdx.x;
    if (i < nE) atomicAdd(&deg[dst[i]], 1);
}

__global__ __launch_bounds__(1024) void k_prefix(const int* __restrict__ deg,
                                                 int* __restrict__ rowptr,
                                                 int* __restrict__ cursor,
                                                 int nNodes) {
    __shared__ int part[1024];
    int tid = threadIdx.x;
    int chunk = (nNodes + 1023) / 1024;
    int beg = tid * chunk;
    int end = beg + chunk; if (end > nNodes) end = nNodes;
    int s = 0;
    for (int i = beg; i < end; ++i) s += deg[i];
    part[tid] = s;
    __syncthreads();
    for (int d = 1; d < 1024; d <<= 1) {
        int t = (tid >= d) ? part[tid - d] : 0;
        __syncthreads();
        part[tid] += t;
        __syncthreads();
    }
    int off = part[tid] - s;  // exclusive prefix for this chunk
    for (int i = beg; i < end; ++i) {
        rowptr[i] = off;
        cursor[i] = off;
        off += deg[i];
    }
    if (tid == 1023) rowptr[nNodes] = part[1023];
}

__global__ __launch_bounds__(256) void k_fill(const int* __restrict__ src,
                                              const int* __restrict__ dst,
                                              int* __restrict__ cursor,
                                              int* __restrict__ col, int nE) {
    int i = blockIdx.x * 256 + threadIdx.x;
    if (i < nE) {
        int d = dst[i];
        int pos = atomicAdd(&cursor[d], 1);
        col[pos] = src[i];
    }
}

// ---------------- aggregation (gather): one wave per node ----------------
// h[n] = x[n] + sum_{e: dst==n} x[src[e]]
__global__ __launch_bounds__(256) void k_agg(const float* __restrict__ x,
                                             const int* __restrict__ rowptr,
                                             const int* __restrict__ col,
                                             float* __restrict__ h,
                                             int nNodes) {
    int n = blockIdx.x * 4 + (threadIdx.x >> 6);
    int lane = threadIdx.x & 63;
    if (n >= nNodes) return;
    int lo = rowptr[n];
    int hi = rowptr[n + 1];
    float acc = x[(size_t)n * 64 + lane];
    int e = lo;
    for (; e + 1 < hi; e += 2) {
        int s0 = col[e];
        int s1 = col[e + 1];
        float v0 = x[(size_t)s0 * 64 + lane];
        float v1 = x[(size_t)s1 * 64 + lane];
        acc += v0;
        acc += v1;
    }
    if (e < hi) acc += x[(size_t)col[e] * 64 + lane];
    h[(size_t)n * 64 + lane] = acc;
}

// ---------------- fused 2-layer MLP (64x64 each) with ReLU ----------------
__global__ __launch_bounds__(256) void k_mlp(const float* __restrict__ h_in,
                                             float* __restrict__ h_out,
                                             const float* __restrict__ W1,
                                             const float* __restrict__ b1,
                                             const float* __restrict__ W2,
                                             const float* __restrict__ b2,
                                             int nNodes) {
    __shared__ float sW[64 * 64];
    __shared__ float sH[64 * 65];
    __shared__ float sH1[64 * 65];
    __shared__ float sB[64];

    int tid = threadIdx.x;
    int n0 = blockIdx.x * 64;

    for (int i = tid; i < 4096; i += 256) sW[i] = W1[i];
    if (tid < 64) sB[tid] = b1[tid];
    for (int i = tid; i < 4096; i += 256) {
        int node = i >> 6, f = i & 63;
        float v = (n0 + node < nNodes) ? h_in[(size_t)(n0 + node) * 64 + f] : 0.f;
        sH[node * 65 + f] = v;
    }
    __syncthreads();

    int nr = (tid >> 4) * 4;
    int fc = (tid & 15) * 4;

    float acc[4][4];
#pragma unroll
    for (int i = 0; i < 4; ++i)
#pragma unroll
        for (int j = 0; j < 4; ++j) acc[i][j] = sB[fc + j];

#pragma unroll 8
    for (int k = 0; k < 64; ++k) {
        float a0 = sH[(nr + 0) * 65 + k];
        float a1 = sH[(nr + 1) * 65 + k];
        float a2 = sH[(nr + 2) * 65 + k];
        float a3 = sH[(nr + 3) * 65 + k];
        float w0 = sW[k * 64 + fc + 0];
        float w1 = sW[k * 64 + fc + 1];
        float w2 = sW[k * 64 + fc + 2];
        float w3 = sW[k * 64 + fc + 3];
        acc[0][0] += a0 * w0; acc[0][1] += a0 * w1; acc[0][2] += a0 * w2; acc[0][3] += a0 * w3;
        acc[1][0] += a1 * w0; acc[1][1] += a1 * w1; acc[1][2] += a1 * w2; acc[1][3] += a1 * w3;
        acc[2][0] += a2 * w0; acc[2][1] += a2 * w1; acc[2][2] += a2 * w2; acc[2][3] += a2 * w3;
        acc[3][0] += a3 * w0; acc[3][1] += a3 * w1; acc[3][2] += a3 * w2; acc[3][3] += a3 * w3;
    }

#pragma unroll
    for (int i = 0; i < 4; ++i)
#pragma unroll
        for (int j = 0; j < 4; ++j)
            sH1[(nr + i) * 65 + fc + j] = fmaxf(acc[i][j], 0.f);

    __syncthreads();
    for (int i = tid; i < 4096; i += 256) sW[i] = W2[i];
    if (tid < 64) sB[tid] = b2[tid];
    __syncthreads();

#pragma unroll
    for (int i = 0; i < 4; ++i)
#pragma unroll
        for (int j = 0; j < 4; ++j) acc[i][j] = sB[fc + j];

#pragma unroll 8
    for (int k = 0; k < 64; ++k) {
        float a0 = sH1[(nr + 0) * 65 + k];
        float a1 = sH1[(nr + 1) * 65 + k];
        float a2 = sH1[(nr + 2) * 65 + k];
        float a3 = sH1[(nr + 3) * 65 + k];
        float w0 = sW[k * 64 + fc + 0];
        float w1 = sW[k * 64 + fc + 1];
        float w2 = sW[k * 64 + fc + 2];
        float w3 = sW[k * 64 + fc + 3];
        acc[0][0] += a0 * w0; acc[0][1] += a0 * w1; acc[0][2] += a0 * w2; acc[0][3] += a0 * w3;
        acc[1][0] += a1 * w0; acc[1][1] += a1 * w1; acc[1][2] += a1 * w2; acc[1][3] += a1 * w3;
        acc[2][0] += a2 * w0; acc[2][1] += a2 * w1; acc[2][2] += a2 * w2; acc[2][3] += a2 * w3;
        acc[3][0] += a3 * w0; acc[3][1] += a3 * w1; acc[3][2] += a3 * w2; acc[3][3] += a3 * w3;
    }

#pragma unroll
    for (int i = 0; i < 4; ++i) {
        int node = n0 + nr + i;
        if (node < nNodes) {
#pragma unroll
            for (int j = 0; j < 4; ++j)
                h_out[(size_t)node * 64 + fc + j] = fmaxf(acc[i][j], 0.f);
        }
    }
}

// ---------------- per-feature sum & sumsq reduction ----------------
__global__ __launch_bounds__(256) void k_stats(const float* __restrict__ h,
                                               float* __restrict__ stats,
                                               int nNodes) {
    int f = threadIdx.x & 63;
    int rl = threadIdx.x >> 6;
    float s = 0.f, q = 0.f;
    for (int r = blockIdx.x * 4 + rl; r < nNodes; r += gridDim.x * 4) {
        float v = h[(size_t)r * 64 + f];
        s += v;
        q += v * v;
    }
    __shared__ float redS[4][64];
    __shared__ float redQ[4][64];
    redS[rl][f] = s;
    redQ[rl][f] = q;
    __syncthreads();
    if (threadIdx.x < 64) {
        float S = redS[0][threadIdx.x] + redS[1][threadIdx.x] + redS[2][threadIdx.x] + redS[3][threadIdx.x];
        float Q = redQ[0][threadIdx.x] + redQ[1][threadIdx.x] + redQ[2][threadIdx.x] + redQ[3][threadIdx.x];
        atomicAdd(&stats[threadIdx.x], S);
        atomicAdd(&stats[64 + threadIdx.x], Q);
    }
}

__global__ void k_bnfin(const float* __restrict__ stats,
                        const float* __restrict__ gamma,
                        const float* __restrict__ beta,
                        float* __restrict__ bnp,
                        float invN) {
    int f = threadIdx.x;
    float mean = stats[f] * invN;
    float var = stats[64 + f] * invN - mean * mean;
    float sc = gamma[f] * rsqrtf(var + 1e-5f);
    bnp[f] = sc;
    bnp[64 + f] = beta[f] - mean * sc;
}

__global__ __launch_bounds__(256) void k_bnapply(const float4* __restrict__ h,
                                                 const float* __restrict__ bnp,
                                                 float4* __restrict__ xout,
                                                 int n4) {
    int i = blockIdx.x * 256 + threadIdx.x;
    if (i >= n4) return;
    int fb = (i * 4) & 63;
    float4 v = h[i];
    float s0 = bnp[fb + 0], s1 = bnp[fb + 1], s2 = bnp[fb + 2], s3 = bnp[fb + 3];
    float t0 = bnp[64 + fb + 0], t1 = bnp[64 + fb + 1], t2 = bnp[64 + fb + 2], t3 = bnp[64 + fb + 3];
    float4 r;
    r.x = fmaxf(v.x * s0 + t0, 0.f);
    r.y = fmaxf(v.y * s1 + t1, 0.f);
    r.z = fmaxf(v.z * s2 + t2, 0.f);
    r.w = fmaxf(v.w * s3 + t3, 0.f);
    xout[i] = r;
}

// ---------------- pooling + final GEMV ----------------
__device__ __forceinline__ int lower_bound_dev(const int* a, int n, int key) {
    int lo = 0, hi = n;
    while (lo < hi) {
        int mid = (lo + hi) >> 1;
        if (a[mid] < key) lo = mid + 1; else hi = mid;
    }
    return lo;
}

__global__ __launch_bounds__(256) void k_pool(const float* __restrict__ x,
                                              const int* __restrict__ batch,
                                              const float* __restrict__ Wf,
                                              const float* __restrict__ bf,
                                              float* __restrict__ out,
                                              int nNodes) {
    int g = blockIdx.x;
    int lo = lower_bound_dev(batch, nNodes, g);
    int hi = lower_bound_dev(batch, nNodes, g + 1);
    int f = threadIdx.x & 63;
    int rl = threadIdx.x >> 6;
    float acc = 0.f;
    for (int r = lo + rl; r < hi; r += 4) acc += x[(size_t)r * 64 + f];
    __shared__ float red[4][64];
    red[rl][f] = acc;
    __syncthreads();
    if (threadIdx.x < 64) {
        float s = red[0][threadIdx.x] + red[1][threadIdx.x] + red[2][threadIdx.x] + red[3][threadIdx.x];
        float p = s * Wf[threadIdx.x];
#pragma unroll
        for (int o = 32; o > 0; o >>= 1) p += __shfl_down(p, o, 64);
        if (threadIdx.x == 0) out[g] = p + bf[0];
    }
}

extern "C" void kernel_launch(void* const* d_in, const int* in_sizes, int n_in,
                              void* d_out, int out_size, void* d_ws, size_t ws_size,
                              hipStream_t stream) {
    const float* x_in  = (const float*)d_in[0];
    const int*   ei    = (const int*)d_in[1];
    const int*   batch = (const int*)d_in[2];
    const float* W1    = (const float*)d_in[3];
    const float* b1    = (const float*)d_in[4];
    const float* W2    = (const float*)d_in[5];
    const float* b2    = (const float*)d_in[6];
    const float* gamma = (const float*)d_in[7];
    const float* beta  = (const float*)d_in[8];
    const float* Wf    = (const float*)d_in[9];
    const float* bf    = (const float*)d_in[10];

    const int nNodes = in_sizes[0] / HIDDEN_C;   // 50000
    const int nE = in_sizes[1] / 2;              // 800000
    const int* src = ei;
    const int* dst = ei + nE;

    const size_t NB = (size_t)nNodes * HIDDEN_C * sizeof(float);  // 12.8 MB
    char* ws = (char*)d_ws;
    float* bufA   = (float*)ws;                       // h work buffer
    float* bufB   = (float*)(ws + NB);                // x ping buffer
    float* stats  = (float*)(ws + 2 * NB);            // 128 floats
    float* bnp    = stats + 128;                      // 128 floats
    int*   deg    = (int*)(ws + 2 * NB + 4096);       // nNodes ints (doubles as cursor)
    int*   rowptr = deg + nNodes;                     // nNodes+1 ints
    int*   col    = rowptr + nNodes + 1;              // nE ints

    const int mlpGrid = (nNodes + 63) / 64;
    const int n4 = nNodes * HIDDEN_C / 4;
    const int applyGrid = (n4 + 255) / 256;
    const int edgeGrid = (nE + 255) / 256;
    const int aggGrid = (nNodes + 3) / 4;

    // ---- build CSR (per launch; deterministic up to fp32 sum order) ----
    hipMemsetAsync(deg, 0, (size_t)nNodes * sizeof(int), stream);
    k_hist<<<edgeGrid, 256, 0, stream>>>(dst, deg, nE);
    k_prefix<<<1, 1024, 0, stream>>>(deg, rowptr, deg /*cursor reuse*/, nNodes);
    // NOTE: k_prefix writes rowptr[i] and cursor[i]=rowptr[i]; deg reused as cursor.
    k_fill<<<edgeGrid, 256, 0, stream>>>(src, dst, deg, col, nE);

    const float* xcur = x_in;
    for (int i = 0; i < 3; ++i) {
        hipMemsetAsync(stats, 0, 128 * sizeof(float), stream);
        k_agg<<<aggGrid, 256, 0, stream>>>(xcur, rowptr, col, bufA, nNodes);
        k_mlp<<<mlpGrid, 256, 0, stream>>>(bufA, bufA,
                                           W1 + (size_t)i * 4096, b1 + (size_t)i * 64,
                                           W2 + (size_t)i * 4096, b2 + (size_t)i * 64,
                                           nNodes);
        k_stats<<<512, 256, 0, stream>>>(bufA, stats, nNodes);
        k_bnfin<<<1, 64, 0, stream>>>(stats, gamma + (size_t)i * 64, beta + (size_t)i * 64,
                                      bnp, 1.f / (float)nNodes);
        k_bnapply<<<applyGrid, 256, 0, stream>>>((const float4*)bufA, bnp, (float4*)bufB, n4);
        xcur = bufB;
    }

    k_pool<<<NUM_GRAPHS_C, 256, 0, stream>>>(bufB, batch, Wf, bf, (float*)d_out, nNodes);
}

// Round 3
// 425.946 us; speedup vs baseline: 1.7152x; 1.2371x over previous
//
#include <hip/hip_runtime.h>
#include <hip/hip_bf16.h>

#define HIDDEN_C 64
#define NUM_GRAPHS_C 256

// ---------------- CSR build ----------------
__global__ __launch_bounds__(256) void k_hist(const int* __restrict__ dst,
                                              int* __restrict__ deg, int nE) {
    int i = blockIdx.x * 256 + threadIdx.x;
    if (i < nE) atomicAdd(&deg[dst[i]], 1);
}

// partial[b] = sum of deg over block b's 1024-element chunk
__global__ __launch_bounds__(256) void k_blocksum(const int* __restrict__ deg,
                                                  int* __restrict__ partial, int nNodes) {
    int base = blockIdx.x * 1024 + threadIdx.x * 4;
    int s = 0;
#pragma unroll
    for (int k = 0; k < 4; ++k) {
        int i = base + k;
        if (i < nNodes) s += deg[i];
    }
    __shared__ int red[256];
    red[threadIdx.x] = s;
    __syncthreads();
    for (int d = 128; d > 0; d >>= 1) {
        if (threadIdx.x < d) red[threadIdx.x] += red[threadIdx.x + d];
        __syncthreads();
    }
    if (threadIdx.x == 0) partial[blockIdx.x] = red[0];
}

// exclusive-scan the (<=256) block partials in LDS; also set rowptr[nNodes]=nE
__global__ __launch_bounds__(256) void k_scanpartial(int* __restrict__ partial,
                                                     int* __restrict__ rowptr_last,
                                                     int nBlocks, int nE) {
    __shared__ int buf[256];
    int tid = threadIdx.x;
    int v = (tid < nBlocks) ? partial[tid] : 0;
    buf[tid] = v;
    __syncthreads();
    for (int d = 1; d < 256; d <<= 1) {
        int t = (tid >= d) ? buf[tid - d] : 0;
        __syncthreads();
        buf[tid] += t;
        __syncthreads();
    }
    if (tid < nBlocks) partial[tid] = buf[tid] - v;  // exclusive prefix
    if (tid == 0) rowptr_last[0] = nE;
}

// rowptr/cursor from deg + scanned partials (cursor may alias deg)
__global__ __launch_bounds__(256) void k_writeptr(const int* __restrict__ deg,
                                                  const int* __restrict__ partial,
                                                  int* __restrict__ rowptr,
                                                  int* __restrict__ cursor, int nNodes) {
    int tid = threadIdx.x;
    int base = blockIdx.x * 1024 + tid * 4;
    int d[4];
    int s = 0;
#pragma unroll
    for (int k = 0; k < 4; ++k) {
        int i = base + k;
        d[k] = (i < nNodes) ? deg[i] : 0;
        s += d[k];
    }
    __shared__ int buf[256];
    buf[tid] = s;
    __syncthreads();
    for (int dd = 1; dd < 256; dd <<= 1) {
        int t = (tid >= dd) ? buf[tid - dd] : 0;
        __syncthreads();
        buf[tid] += t;
        __syncthreads();
    }
    int off = partial[blockIdx.x] + buf[tid] - s;
#pragma unroll
    for (int k = 0; k < 4; ++k) {
        int i = base + k;
        if (i < nNodes) {
            rowptr[i] = off;
            cursor[i] = off;
            off += d[k];
        }
    }
}

__global__ __launch_bounds__(256) void k_fill(const int* __restrict__ src,
                                              const int* __restrict__ dst,
                                              int* __restrict__ cursor,
                                              int* __restrict__ col, int nE) {
    int i = blockIdx.x * 256 + threadIdx.x;
    if (i < nE) {
        int d = dst[i];
        int pos = atomicAdd(&cursor[d], 1);
        col[pos] = src[i];
    }
}

// ---------------- aggregation (gather): one wave per node ----------------
__global__ __launch_bounds__(256) void k_agg(const float* __restrict__ x,
                                             const int* __restrict__ rowptr,
                                             const int* __restrict__ col,
                                             float* __restrict__ h,
                                             int nNodes) {
    int n = blockIdx.x * 4 + (threadIdx.x >> 6);
    int lane = threadIdx.x & 63;
    if (n >= nNodes) return;
    int lo = rowptr[n];
    int hi = rowptr[n + 1];
    float acc = x[(size_t)n * 64 + lane];
    int e = lo;
    for (; e + 1 < hi; e += 2) {
        int s0 = col[e];
        int s1 = col[e + 1];
        float v0 = x[(size_t)s0 * 64 + lane];
        float v1 = x[(size_t)s1 * 64 + lane];
        acc += v0;
        acc += v1;
    }
    if (e < hi) acc += x[(size_t)col[e] * 64 + lane];
    h[(size_t)n * 64 + lane] = acc;
}

// ---------------- fused 2-layer MLP + BN-stats epilogue ----------------
__global__ __launch_bounds__(256) void k_mlp(const float* __restrict__ h_in,
                                             float* __restrict__ h_out,
                                             const float* __restrict__ W1,
                                             const float* __restrict__ b1,
                                             const float* __restrict__ W2,
                                             const float* __restrict__ b2,
                                             float* __restrict__ stats,
                                             int nNodes) {
    __shared__ float sW[64 * 64];
    __shared__ float sH[64 * 65];
    __shared__ float sH1[64 * 65];
    __shared__ float sB[64];

    int tid = threadIdx.x;
    int n0 = blockIdx.x * 64;

    for (int i = tid; i < 4096; i += 256) sW[i] = W1[i];
    if (tid < 64) sB[tid] = b1[tid];
    for (int i = tid; i < 4096; i += 256) {
        int node = i >> 6, f = i & 63;
        float v = (n0 + node < nNodes) ? h_in[(size_t)(n0 + node) * 64 + f] : 0.f;
        sH[node * 65 + f] = v;
    }
    __syncthreads();

    int nr = (tid >> 4) * 4;
    int fc = (tid & 15) * 4;

    float acc[4][4];
#pragma unroll
    for (int i = 0; i < 4; ++i)
#pragma unroll
        for (int j = 0; j < 4; ++j) acc[i][j] = sB[fc + j];

#pragma unroll 8
    for (int k = 0; k < 64; ++k) {
        float a0 = sH[(nr + 0) * 65 + k];
        float a1 = sH[(nr + 1) * 65 + k];
        float a2 = sH[(nr + 2) * 65 + k];
        float a3 = sH[(nr + 3) * 65 + k];
        float w0 = sW[k * 64 + fc + 0];
        float w1 = sW[k * 64 + fc + 1];
        float w2 = sW[k * 64 + fc + 2];
        float w3 = sW[k * 64 + fc + 3];
        acc[0][0] += a0 * w0; acc[0][1] += a0 * w1; acc[0][2] += a0 * w2; acc[0][3] += a0 * w3;
        acc[1][0] += a1 * w0; acc[1][1] += a1 * w1; acc[1][2] += a1 * w2; acc[1][3] += a1 * w3;
        acc[2][0] += a2 * w0; acc[2][1] += a2 * w1; acc[2][2] += a2 * w2; acc[2][3] += a2 * w3;
        acc[3][0] += a3 * w0; acc[3][1] += a3 * w1; acc[3][2] += a3 * w2; acc[3][3] += a3 * w3;
    }

#pragma unroll
    for (int i = 0; i < 4; ++i)
#pragma unroll
        for (int j = 0; j < 4; ++j)
            sH1[(nr + i) * 65 + fc + j] = fmaxf(acc[i][j], 0.f);

    __syncthreads();  // sH reads all done; sW/sB reads all done
    for (int i = tid; i < 4096; i += 256) sW[i] = W2[i];
    if (tid < 64) sB[tid] = b2[tid];
    __syncthreads();

#pragma unroll
    for (int i = 0; i < 4; ++i)
#pragma unroll
        for (int j = 0; j < 4; ++j) acc[i][j] = sB[fc + j];

#pragma unroll 8
    for (int k = 0; k < 64; ++k) {
        float a0 = sH1[(nr + 0) * 65 + k];
        float a1 = sH1[(nr + 1) * 65 + k];
        float a2 = sH1[(nr + 2) * 65 + k];
        float a3 = sH1[(nr + 3) * 65 + k];
        float w0 = sW[k * 64 + fc + 0];
        float w1 = sW[k * 64 + fc + 1];
        float w2 = sW[k * 64 + fc + 2];
        float w3 = sW[k * 64 + fc + 3];
        acc[0][0] += a0 * w0; acc[0][1] += a0 * w1; acc[0][2] += a0 * w2; acc[0][3] += a0 * w3;
        acc[1][0] += a1 * w0; acc[1][1] += a1 * w1; acc[1][2] += a1 * w2; acc[1][3] += a1 * w3;
        acc[2][0] += a2 * w0; acc[2][1] += a2 * w1; acc[2][2] += a2 * w2; acc[2][3] += a2 * w3;
        acc[3][0] += a3 * w0; acc[3][1] += a3 * w1; acc[3][2] += a3 * w2; acc[3][3] += a3 * w3;
    }

    // epilogue: relu, store, per-feature partial stats (sum, sumsq)
    float sj[4] = {0.f, 0.f, 0.f, 0.f};
    float qj[4] = {0.f, 0.f, 0.f, 0.f};
#pragma unroll
    for (int i = 0; i < 4; ++i) {
        int node = n0 + nr + i;
        if (node < nNodes) {
#pragma unroll
            for (int j = 0; j < 4; ++j) {
                float r = fmaxf(acc[i][j], 0.f);
                h_out[(size_t)node * 64 + fc + j] = r;
                sj[j] += r;
                qj[j] += r * r;
            }
        }
    }

    // sH is dead after GEMM-1; reuse as 16x64 stats scratch (needs 2048 floats)
    float* sS = sH;
    float* sQ = sH + 1024;
    __syncthreads();  // ensure all sH1 reads done before... (sH1 untouched; barrier for sS reuse ordering)
#pragma unroll
    for (int j = 0; j < 4; ++j) {
        sS[(tid >> 4) * 64 + fc + j] = sj[j];
        sQ[(tid >> 4) * 64 + fc + j] = qj[j];
    }
    __syncthreads();
    if (tid < 64) {
        float S = 0.f;
#pragma unroll
        for (int r = 0; r < 16; ++r) S += sS[r * 64 + tid];
        atomicAdd(&stats[tid], S);
    } else if (tid < 128) {
        int f = tid - 64;
        float Q = 0.f;
#pragma unroll
        for (int r = 0; r < 16; ++r) Q += sQ[r * 64 + f];
        atomicAdd(&stats[64 + f], Q);
    }
}

// ---------------- BN finalize (per-block, redundant) + apply + ReLU ----------------
__global__ __launch_bounds__(256) void k_bnapply(const float4* __restrict__ h,
                                                 const float* __restrict__ stats,
                                                 const float* __restrict__ gamma,
                                                 const float* __restrict__ beta,
                                                 float4* __restrict__ xout,
                                                 int n4, float invN) {
    __shared__ float sc[64], sh[64];
    int tid = threadIdx.x;
    if (tid < 64) {
        float mean = stats[tid] * invN;
        float var = stats[64 + tid] * invN - mean * mean;
        float s = gamma[tid] * rsqrtf(var + 1e-5f);
        sc[tid] = s;
        sh[tid] = beta[tid] - mean * s;
    }
    __syncthreads();
    int i = blockIdx.x * 256 + tid;
    if (i >= n4) return;
    int fb = (i * 4) & 63;
    float4 v = h[i];
    float4 r;
    r.x = fmaxf(v.x * sc[fb + 0] + sh[fb + 0], 0.f);
    r.y = fmaxf(v.y * sc[fb + 1] + sh[fb + 1], 0.f);
    r.z = fmaxf(v.z * sc[fb + 2] + sh[fb + 2], 0.f);
    r.w = fmaxf(v.w * sc[fb + 3] + sh[fb + 3], 0.f);
    xout[i] = r;
}

// ---------------- pooling + final GEMV ----------------
__device__ __forceinline__ int lower_bound_dev(const int* a, int n, int key) {
    int lo = 0, hi = n;
    while (lo < hi) {
        int mid = (lo + hi) >> 1;
        if (a[mid] < key) lo = mid + 1; else hi = mid;
    }
    return lo;
}

__global__ __launch_bounds__(256) void k_pool(const float* __restrict__ x,
                                              const int* __restrict__ batch,
                                              const float* __restrict__ Wf,
                                              const float* __restrict__ bf,
                                              float* __restrict__ out,
                                              int nNodes) {
    int g = blockIdx.x;
    int lo = lower_bound_dev(batch, nNodes, g);
    int hi = lower_bound_dev(batch, nNodes, g + 1);
    int f = threadIdx.x & 63;
    int rl = threadIdx.x >> 6;
    float acc = 0.f;
    for (int r = lo + rl; r < hi; r += 4) acc += x[(size_t)r * 64 + f];
    __shared__ float red[4][64];
    red[rl][f] = acc;
    __syncthreads();
    if (threadIdx.x < 64) {
        float s = red[0][threadIdx.x] + red[1][threadIdx.x] + red[2][threadIdx.x] + red[3][threadIdx.x];
        float p = s * Wf[threadIdx.x];
#pragma unroll
        for (int o = 32; o > 0; o >>= 1) p += __shfl_down(p, o, 64);
        if (threadIdx.x == 0) out[g] = p + bf[0];
    }
}

extern "C" void kernel_launch(void* const* d_in, const int* in_sizes, int n_in,
                              void* d_out, int out_size, void* d_ws, size_t ws_size,
                              hipStream_t stream) {
    const float* x_in  = (const float*)d_in[0];
    const int*   ei    = (const int*)d_in[1];
    const int*   batch = (const int*)d_in[2];
    const float* W1    = (const float*)d_in[3];
    const float* b1    = (const float*)d_in[4];
    const float* W2    = (const float*)d_in[5];
    const float* b2    = (const float*)d_in[6];
    const float* gamma = (const float*)d_in[7];
    const float* beta  = (const float*)d_in[8];
    const float* Wf    = (const float*)d_in[9];
    const float* bf    = (const float*)d_in[10];

    const int nNodes = in_sizes[0] / HIDDEN_C;   // 50000
    const int nE = in_sizes[1] / 2;              // 800000
    const int* src = ei;
    const int* dst = ei + nE;

    const size_t NB = (size_t)nNodes * HIDDEN_C * sizeof(float);  // 12.8 MB
    char* ws = (char*)d_ws;
    float* bufA    = (float*)ws;
    float* bufB    = (float*)(ws + NB);
    float* stats   = (float*)(ws + 2 * NB);           // 128 floats
    int*   deg     = (int*)(ws + 2 * NB + 4096);      // nNodes ints (aliases cursor)
    int*   rowptr  = deg + nNodes;                    // nNodes+1 ints
    int*   partial = rowptr + nNodes + 1;             // 256 ints
    int*   col     = partial + 256;                   // nE ints

    const int mlpGrid = (nNodes + 63) / 64;
    const int n4 = nNodes * HIDDEN_C / 4;
    const int applyGrid = (n4 + 255) / 256;
    const int edgeGrid = (nE + 255) / 256;
    const int aggGrid = (nNodes + 3) / 4;
    const int scanBlocks = (nNodes + 1023) / 1024;    // 49

    // ---- build CSR ----
    hipMemsetAsync(deg, 0, (size_t)nNodes * sizeof(int), stream);
    k_hist<<<edgeGrid, 256, 0, stream>>>(dst, deg, nE);
    k_blocksum<<<scanBlocks, 256, 0, stream>>>(deg, partial, nNodes);
    k_scanpartial<<<1, 256, 0, stream>>>(partial, rowptr + nNodes, scanBlocks, nE);
    k_writeptr<<<scanBlocks, 256, 0, stream>>>(deg, partial, rowptr, deg /*cursor*/, nNodes);
    k_fill<<<edgeGrid, 256, 0, stream>>>(src, dst, deg, col, nE);

    const float* xcur = x_in;
    for (int i = 0; i < 3; ++i) {
        hipMemsetAsync(stats, 0, 128 * sizeof(float), stream);
        k_agg<<<aggGrid, 256, 0, stream>>>(xcur, rowptr, col, bufA, nNodes);
        k_mlp<<<mlpGrid, 256, 0, stream>>>(bufA, bufA,
                                           W1 + (size_t)i * 4096, b1 + (size_t)i * 64,
                                           W2 + (size_t)i * 4096, b2 + (size_t)i * 64,
                                           stats, nNodes);
        k_bnapply<<<applyGrid, 256, 0, stream>>>((const float4*)bufA, stats,
                                                 gamma + (size_t)i * 64, beta + (size_t)i * 64,
                                                 (float4*)bufB, n4, 1.f / (float)nNodes);
        xcur = bufB;
    }

    k_pool<<<NUM_GRAPHS_C, 256, 0, stream>>>(bufB, batch, Wf, bf, (float*)d_out, nNodes);
}

// Round 4
// 384.728 us; speedup vs baseline: 1.8990x; 1.1071x over previous
//
#include <hip/hip_runtime.h>

#define HIDDEN_C 64

__device__ __forceinline__ float4 f4zero() { return make_float4(0.f, 0.f, 0.f, 0.f); }

#define SWZ(node) ((((node) >> 2) & 7) << 4)

// ---------------- CSR build ----------------
__global__ __launch_bounds__(256) void k_hist(const int* __restrict__ dst,
                                              int* __restrict__ deg, int nE) {
    int i = blockIdx.x * 256 + threadIdx.x;
    if (i < nE) atomicAdd(&deg[dst[i]], 1);
}

__global__ __launch_bounds__(256) void k_blocksum(const int* __restrict__ deg,
                                                  int* __restrict__ partial, int nNodes) {
    int base = blockIdx.x * 1024 + threadIdx.x * 4;
    int s = 0;
#pragma unroll
    for (int k = 0; k < 4; ++k) {
        int i = base + k;
        if (i < nNodes) s += deg[i];
    }
    __shared__ int red[256];
    red[threadIdx.x] = s;
    __syncthreads();
    for (int d = 128; d > 0; d >>= 1) {
        if (threadIdx.x < d) red[threadIdx.x] += red[threadIdx.x + d];
        __syncthreads();
    }
    if (threadIdx.x == 0) partial[blockIdx.x] = red[0];
}

__global__ __launch_bounds__(256) void k_scanpartial(int* __restrict__ partial,
                                                     int* __restrict__ rowptr_last,
                                                     int nBlocks, int nE) {
    __shared__ int buf[256];
    int tid = threadIdx.x;
    int v = (tid < nBlocks) ? partial[tid] : 0;
    buf[tid] = v;
    __syncthreads();
    for (int d = 1; d < 256; d <<= 1) {
        int t = (tid >= d) ? buf[tid - d] : 0;
        __syncthreads();
        buf[tid] += t;
        __syncthreads();
    }
    if (tid < nBlocks) partial[tid] = buf[tid] - v;
    if (tid == 0) rowptr_last[0] = nE;
}

__global__ __launch_bounds__(256) void k_writeptr(const int* __restrict__ deg,
                                                  const int* __restrict__ partial,
                                                  int* __restrict__ rowptr,
                                                  int* __restrict__ cursor, int nNodes) {
    int tid = threadIdx.x;
    int base = blockIdx.x * 1024 + tid * 4;
    int d[4];
    int s = 0;
#pragma unroll
    for (int k = 0; k < 4; ++k) {
        int i = base + k;
        d[k] = (i < nNodes) ? deg[i] : 0;
        s += d[k];
    }
    __shared__ int buf[256];
    buf[tid] = s;
    __syncthreads();
    for (int dd = 1; dd < 256; dd <<= 1) {
        int t = (tid >= dd) ? buf[tid - dd] : 0;
        __syncthreads();
        buf[tid] += t;
        __syncthreads();
    }
    int off = partial[blockIdx.x] + buf[tid] - s;
#pragma unroll
    for (int k = 0; k < 4; ++k) {
        int i = base + k;
        if (i < nNodes) {
            rowptr[i] = off;
            cursor[i] = off;
            off += d[k];
        }
    }
}

__global__ __launch_bounds__(256) void k_fill(const int* __restrict__ src,
                                              const int* __restrict__ dst,
                                              int* __restrict__ cursor,
                                              int* __restrict__ col, int nE) {
    int i = blockIdx.x * 256 + threadIdx.x;
    if (i < nE) {
        int d = dst[i];
        int pos = atomicAdd(&cursor[d], 1);
        col[pos] = src[i];
    }
}

// ---------------- fused BN(prev layer) + gather aggregation ----------------
// out[n] = t(x[n]) + sum_{e: dst==n} t(x[src[e]]),  t = DOBN ? relu(v*sc+sh) : v
// wave = 1 node; 4 lane-groups x 16 lanes (float4) -> 4 edges per load instr
template <bool DOBN>
__global__ __launch_bounds__(256) void k_aggbn(const float4* __restrict__ x4,
                                               const int* __restrict__ rowptr,
                                               const int* __restrict__ col,
                                               const float* __restrict__ stats,
                                               const float* __restrict__ gamma,
                                               const float* __restrict__ beta,
                                               float4* __restrict__ h4,
                                               int nNodes, float invN) {
    int wid = threadIdx.x >> 6;
    int lane = threadIdx.x & 63;
    int grp = lane >> 4;
    int l16 = lane & 15;
    int n = blockIdx.x * 4 + wid;
    if (n >= nNodes) return;

    float4 sc = make_float4(1.f, 1.f, 1.f, 1.f);
    float4 sh = f4zero();
    if (DOBN) {
        float4 s  = ((const float4*)stats)[l16];
        float4 q  = ((const float4*)stats)[16 + l16];
        float4 ga = ((const float4*)gamma)[l16];
        float4 be = ((const float4*)beta)[l16];
        float m;
        m = s.x * invN; sc.x = ga.x * rsqrtf(q.x * invN - m * m + 1e-5f); sh.x = be.x - m * sc.x;
        m = s.y * invN; sc.y = ga.y * rsqrtf(q.y * invN - m * m + 1e-5f); sh.y = be.y - m * sc.y;
        m = s.z * invN; sc.z = ga.z * rsqrtf(q.z * invN - m * m + 1e-5f); sh.z = be.z - m * sc.z;
        m = s.w * invN; sc.w = ga.w * rsqrtf(q.w * invN - m * m + 1e-5f); sh.w = be.w - m * sc.w;
    }

    float4 acc = f4zero();
    {
        float4 v = x4[(size_t)n * 16 + l16];
        if (DOBN) {
            v.x = fmaxf(fmaf(v.x, sc.x, sh.x), 0.f);
            v.y = fmaxf(fmaf(v.y, sc.y, sh.y), 0.f);
            v.z = fmaxf(fmaf(v.z, sc.z, sh.z), 0.f);
            v.w = fmaxf(fmaf(v.w, sc.w, sh.w), 0.f);
        }
        if (grp == 0) acc = v;
    }

    int lo = rowptr[n], hi = rowptr[n + 1];
    for (int e = lo; e < hi; e += 4) {
        int ee = e + grp;
        bool ok = ee < hi;
        int idx = col[ok ? ee : (hi - 1)];
        float4 v = x4[(size_t)idx * 16 + l16];
        if (DOBN) {
            v.x = fmaxf(fmaf(v.x, sc.x, sh.x), 0.f);
            v.y = fmaxf(fmaf(v.y, sc.y, sh.y), 0.f);
            v.z = fmaxf(fmaf(v.z, sc.z, sh.z), 0.f);
            v.w = fmaxf(fmaf(v.w, sc.w, sh.w), 0.f);
        }
        if (ok) {
            acc.x += v.x; acc.y += v.y; acc.z += v.z; acc.w += v.w;
        }
    }

    acc.x += __shfl_xor(acc.x, 16, 64); acc.y += __shfl_xor(acc.y, 16, 64);
    acc.z += __shfl_xor(acc.z, 16, 64); acc.w += __shfl_xor(acc.w, 16, 64);
    acc.x += __shfl_xor(acc.x, 32, 64); acc.y += __shfl_xor(acc.y, 32, 64);
    acc.z += __shfl_xor(acc.z, 32, 64); acc.w += __shfl_xor(acc.w, 32, 64);

    if (lane < 16) h4[(size_t)n * 16 + l16] = acc;
}

// ---------------- fused 2-layer MLP + BN-stats (b128 LDS, swizzled) ----------------
#define KSTEP(AC, WV)                                                       \
    acc00 = fmaf(a0.AC, WV.x, acc00); acc01 = fmaf(a0.AC, WV.y, acc01);     \
    acc02 = fmaf(a0.AC, WV.z, acc02); acc03 = fmaf(a0.AC, WV.w, acc03);     \
    acc10 = fmaf(a1.AC, WV.x, acc10); acc11 = fmaf(a1.AC, WV.y, acc11);     \
    acc12 = fmaf(a1.AC, WV.z, acc12); acc13 = fmaf(a1.AC, WV.w, acc13);     \
    acc20 = fmaf(a2.AC, WV.x, acc20); acc21 = fmaf(a2.AC, WV.y, acc21);     \
    acc22 = fmaf(a2.AC, WV.z, acc22); acc23 = fmaf(a2.AC, WV.w, acc23);     \
    acc30 = fmaf(a3.AC, WV.x, acc30); acc31 = fmaf(a3.AC, WV.y, acc31);     \
    acc32 = fmaf(a3.AC, WV.z, acc32); acc33 = fmaf(a3.AC, WV.w, acc33);

#define GEMM_LOOP(SRC)                                                                     \
    _Pragma("unroll")                                                                      \
    for (int kb = 0; kb < 16; ++kb) {                                                      \
        int kB = kb * 16;                                                                  \
        float4 a0 = *(const float4*)((const char*)SRC + (nr + 0) * 256 + (kB ^ SWZ(nr + 0))); \
        float4 a1 = *(const float4*)((const char*)SRC + (nr + 1) * 256 + (kB ^ SWZ(nr + 1))); \
        float4 a2 = *(const float4*)((const char*)SRC + (nr + 2) * 256 + (kB ^ SWZ(nr + 2))); \
        float4 a3 = *(const float4*)((const char*)SRC + (nr + 3) * 256 + (kB ^ SWZ(nr + 3))); \
        const char* wrow = (const char*)sW + kb * 1024 + fc * 4;                           \
        float4 w0 = *(const float4*)(wrow);                                               \
        float4 w1 = *(const float4*)(wrow + 256);                                         \
        float4 w2 = *(const float4*)(wrow + 512);                                         \
        float4 w3 = *(const float4*)(wrow + 768);                                         \
        KSTEP(x, w0) KSTEP(y, w1) KSTEP(z, w2) KSTEP(w, w3)                                \
    }

__global__ __launch_bounds__(256) void k_mlp(const float4* __restrict__ h_in4,
                                             float4* __restrict__ h_out4,
                                             const float4* __restrict__ W1_4,
                                             const float* __restrict__ b1,
                                             const float4* __restrict__ W2_4,
                                             const float* __restrict__ b2,
                                             float* __restrict__ stats,
                                             int nNodes) {
    __shared__ float sA[4096];
    __shared__ float sW[4096];
    __shared__ float sH1[4096];

    int tid = threadIdx.x;
    int n0 = blockIdx.x * 64;
    int nr = (tid >> 4) * 4;
    int fc = (tid & 15) * 4;

#pragma unroll
    for (int it = 0; it < 4; ++it) {
        int i = it * 256 + tid;
        ((float4*)sW)[i] = W1_4[i];
        int node = i >> 4, slot = i & 15;
        float4 v = (n0 + node < nNodes) ? h_in4[(size_t)(n0 + node) * 16 + slot] : f4zero();
        *(float4*)((char*)sA + node * 256 + ((slot * 16) ^ SWZ(node))) = v;
    }
    __syncthreads();

    float4 bias = ((const float4*)b1)[tid & 15];
    float acc00 = bias.x, acc01 = bias.y, acc02 = bias.z, acc03 = bias.w;
    float acc10 = bias.x, acc11 = bias.y, acc12 = bias.z, acc13 = bias.w;
    float acc20 = bias.x, acc21 = bias.y, acc22 = bias.z, acc23 = bias.w;
    float acc30 = bias.x, acc31 = bias.y, acc32 = bias.z, acc33 = bias.w;

    GEMM_LOOP(sA)

    {
        float4 r;
        r.x = fmaxf(acc00, 0.f); r.y = fmaxf(acc01, 0.f); r.z = fmaxf(acc02, 0.f); r.w = fmaxf(acc03, 0.f);
        *(float4*)((char*)sH1 + (nr + 0) * 256 + ((fc * 4) ^ SWZ(nr + 0))) = r;
        r.x = fmaxf(acc10, 0.f); r.y = fmaxf(acc11, 0.f); r.z = fmaxf(acc12, 0.f); r.w = fmaxf(acc13, 0.f);
        *(float4*)((char*)sH1 + (nr + 1) * 256 + ((fc * 4) ^ SWZ(nr + 1))) = r;
        r.x = fmaxf(acc20, 0.f); r.y = fmaxf(acc21, 0.f); r.z = fmaxf(acc22, 0.f); r.w = fmaxf(acc23, 0.f);
        *(float4*)((char*)sH1 + (nr + 2) * 256 + ((fc * 4) ^ SWZ(nr + 2))) = r;
        r.x = fmaxf(acc30, 0.f); r.y = fmaxf(acc31, 0.f); r.z = fmaxf(acc32, 0.f); r.w = fmaxf(acc33, 0.f);
        *(float4*)((char*)sH1 + (nr + 3) * 256 + ((fc * 4) ^ SWZ(nr + 3))) = r;
    }

    __syncthreads();  // sW (W1) reads + sH1 writes complete
#pragma unroll
    for (int it = 0; it < 4; ++it) {
        int i = it * 256 + tid;
        ((float4*)sW)[i] = W2_4[i];
    }
    __syncthreads();

    bias = ((const float4*)b2)[tid & 15];
    acc00 = bias.x; acc01 = bias.y; acc02 = bias.z; acc03 = bias.w;
    acc10 = bias.x; acc11 = bias.y; acc12 = bias.z; acc13 = bias.w;
    acc20 = bias.x; acc21 = bias.y; acc22 = bias.z; acc23 = bias.w;
    acc30 = bias.x; acc31 = bias.y; acc32 = bias.z; acc33 = bias.w;

    GEMM_LOOP(sH1)

    // epilogue: relu, store, per-feature partial stats
    float sj0 = 0.f, sj1 = 0.f, sj2 = 0.f, sj3 = 0.f;
    float qj0 = 0.f, qj1 = 0.f, qj2 = 0.f, qj3 = 0.f;
    {
        int node = n0 + nr;
        float4 r;
        if (node + 0 < nNodes) {
            r.x = fmaxf(acc00, 0.f); r.y = fmaxf(acc01, 0.f); r.z = fmaxf(acc02, 0.f); r.w = fmaxf(acc03, 0.f);
            h_out4[(size_t)(node + 0) * 16 + (fc >> 2)] = r;
            sj0 += r.x; qj0 += r.x * r.x; sj1 += r.y; qj1 += r.y * r.y;
            sj2 += r.z; qj2 += r.z * r.z; sj3 += r.w; qj3 += r.w * r.w;
        }
        if (node + 1 < nNodes) {
            r.x = fmaxf(acc10, 0.f); r.y = fmaxf(acc11, 0.f); r.z = fmaxf(acc12, 0.f); r.w = fmaxf(acc13, 0.f);
            h_out4[(size_t)(node + 1) * 16 + (fc >> 2)] = r;
            sj0 += r.x; qj0 += r.x * r.x; sj1 += r.y; qj1 += r.y * r.y;
            sj2 += r.z; qj2 += r.z * r.z; sj3 += r.w; qj3 += r.w * r.w;
        }
        if (node + 2 < nNodes) {
            r.x = fmaxf(acc20, 0.f); r.y = fmaxf(acc21, 0.f); r.z = fmaxf(acc22, 0.f); r.w = fmaxf(acc23, 0.f);
            h_out4[(size_t)(node + 2) * 16 + (fc >> 2)] = r;
            sj0 += r.x; qj0 += r.x * r.x; sj1 += r.y; qj1 += r.y * r.y;
            sj2 += r.z; qj2 += r.z * r.z; sj3 += r.w; qj3 += r.w * r.w;
        }
        if (node + 3 < nNodes) {
            r.x = fmaxf(acc30, 0.f); r.y = fmaxf(acc31, 0.f); r.z = fmaxf(acc32, 0.f); r.w = fmaxf(acc33, 0.f);
            h_out4[(size_t)(node + 3) * 16 + (fc >> 2)] = r;
            sj0 += r.x; qj0 += r.x * r.x; sj1 += r.y; qj1 += r.y * r.y;
            sj2 += r.z; qj2 += r.z * r.z; sj3 += r.w; qj3 += r.w * r.w;
        }
    }

    float* sS = sA;        // sA dead after GEMM1
    float* sQ = sA + 1024;
    int rrow = tid >> 4;
    sS[rrow * 64 + fc + 0] = sj0; sS[rrow * 64 + fc + 1] = sj1;
    sS[rrow * 64 + fc + 2] = sj2; sS[rrow * 64 + fc + 3] = sj3;
    sQ[rrow * 64 + fc + 0] = qj0; sQ[rrow * 64 + fc + 1] = qj1;
    sQ[rrow * 64 + fc + 2] = qj2; sQ[rrow * 64 + fc + 3] = qj3;
    __syncthreads();
    if (tid < 64) {
        float S = 0.f;
#pragma unroll
        for (int r = 0; r < 16; ++r) S += sS[r * 64 + tid];
        atomicAdd(&stats[tid], S);
    } else if (tid < 128) {
        int f = tid - 64;
        float Q = 0.f;
#pragma unroll
        for (int r = 0; r < 16; ++r) Q += sQ[r * 64 + f];
        atomicAdd(&stats[64 + f], Q);
    }
}

// ---------------- pooling (BN3 fused) + final GEMV ----------------
__device__ __forceinline__ int lower_bound_dev(const int* a, int n, int key) {
    int lo = 0, hi = n;
    while (lo < hi) {
        int mid = (lo + hi) >> 1;
        if (a[mid] < key) lo = mid + 1; else hi = mid;
    }
    return lo;
}

__global__ __launch_bounds__(256) void k_pool(const float4* __restrict__ x4,
                                              const int* __restrict__ batch,
                                              const float* __restrict__ stats,
                                              const float* __restrict__ gamma,
                                              const float* __restrict__ beta,
                                              const float* __restrict__ Wf,
                                              const float* __restrict__ bf,
                                              float* __restrict__ out,
                                              int nNodes, float invN) {
    int wid = threadIdx.x >> 6;
    int lane = threadIdx.x & 63;
    int grp = lane >> 4;
    int l16 = lane & 15;
    int g = blockIdx.x * 4 + wid;

    float4 sc, sh;
    {
        float4 s  = ((const float4*)stats)[l16];
        float4 q  = ((const float4*)stats)[16 + l16];
        float4 ga = ((const float4*)gamma)[l16];
        float4 be = ((const float4*)beta)[l16];
        float m;
        m = s.x * invN; sc.x = ga.x * rsqrtf(q.x * invN - m * m + 1e-5f); sh.x = be.x - m * sc.x;
        m = s.y * invN; sc.y = ga.y * rsqrtf(q.y * invN - m * m + 1e-5f); sh.y = be.y - m * sc.y;
        m = s.z * invN; sc.z = ga.z * rsqrtf(q.z * invN - m * m + 1e-5f); sh.z = be.z - m * sc.z;
        m = s.w * invN; sc.w = ga.w * rsqrtf(q.w * invN - m * m + 1e-5f); sh.w = be.w - m * sc.w;
    }

    int lo = lower_bound_dev(batch, nNodes, g);
    int hi = lower_bound_dev(batch, nNodes, g + 1);

    float4 acc = f4zero();
    for (int r = lo + grp; r < hi; r += 4) {
        float4 v = x4[(size_t)r * 16 + l16];
        acc.x += fmaxf(fmaf(v.x, sc.x, sh.x), 0.f);
        acc.y += fmaxf(fmaf(v.y, sc.y, sh.y), 0.f);
        acc.z += fmaxf(fmaf(v.z, sc.z, sh.z), 0.f);
        acc.w += fmaxf(fmaf(v.w, sc.w, sh.w), 0.f);
    }
    acc.x += __shfl_xor(acc.x, 16, 64); acc.y += __shfl_xor(acc.y, 16, 64);
    acc.z += __shfl_xor(acc.z, 16, 64); acc.w += __shfl_xor(acc.w, 16, 64);
    acc.x += __shfl_xor(acc.x, 32, 64); acc.y += __shfl_xor(acc.y, 32, 64);
    acc.z += __shfl_xor(acc.z, 32, 64); acc.w += __shfl_xor(acc.w, 32, 64);

    float4 wf = ((const float4*)Wf)[l16];
    float p = acc.x * wf.x + acc.y * wf.y + acc.z * wf.z + acc.w * wf.w;
    p += __shfl_xor(p, 1, 64);
    p += __shfl_xor(p, 2, 64);
    p += __shfl_xor(p, 4, 64);
    p += __shfl_xor(p, 8, 64);
    if (lane == 0) out[g] = p + bf[0];
}

extern "C" void kernel_launch(void* const* d_in, const int* in_sizes, int n_in,
                              void* d_out, int out_size, void* d_ws, size_t ws_size,
                              hipStream_t stream) {
    const float* x_in  = (const float*)d_in[0];
    const int*   ei    = (const int*)d_in[1];
    const int*   batch = (const int*)d_in[2];
    const float* W1    = (const float*)d_in[3];
    const float* b1    = (const float*)d_in[4];
    const float* W2    = (const float*)d_in[5];
    const float* b2    = (const float*)d_in[6];
    const float* gamma = (const float*)d_in[7];
    const float* beta  = (const float*)d_in[8];
    const float* Wf    = (const float*)d_in[9];
    const float* bf    = (const float*)d_in[10];

    const int nNodes = in_sizes[0] / HIDDEN_C;   // 50000
    const int nE = in_sizes[1] / 2;              // 800000
    const int* src = ei;
    const int* dst = ei + nE;

    const size_t NB = (size_t)nNodes * HIDDEN_C * sizeof(float);  // 12.8 MB
    char* ws = (char*)d_ws;
    float* bufA    = (float*)ws;
    float* bufB    = (float*)(ws + NB);
    float* stats   = (float*)(ws + 2 * NB);           // 3 x 128 floats
    int*   deg     = (int*)(ws + 2 * NB + 4096);      // nNodes ints (aliases cursor)
    int*   rowptr  = deg + nNodes;                    // nNodes+1 ints
    int*   partial = rowptr + nNodes + 1;             // 256 ints
    int*   col     = partial + 256;                   // nE ints

    const int mlpGrid = (nNodes + 63) / 64;
    const int edgeGrid = (nE + 255) / 256;
    const int aggGrid = (nNodes + 3) / 4;
    const int scanBlocks = (nNodes + 1023) / 1024;
    const float invN = 1.f / (float)nNodes;

    // ---- build CSR + zero stats ----
    hipMemsetAsync(stats, 0, 384 * sizeof(float), stream);
    hipMemsetAsync(deg, 0, (size_t)nNodes * sizeof(int), stream);
    k_hist<<<edgeGrid, 256, 0, stream>>>(dst, deg, nE);
    k_blocksum<<<scanBlocks, 256, 0, stream>>>(deg, partial, nNodes);
    k_scanpartial<<<1, 256, 0, stream>>>(partial, rowptr + nNodes, scanBlocks, nE);
    k_writeptr<<<scanBlocks, 256, 0, stream>>>(deg, partial, rowptr, deg /*cursor*/, nNodes);
    k_fill<<<edgeGrid, 256, 0, stream>>>(src, dst, deg, col, nE);

    const float* prev_h = x_in;   // pre-BN h of previous layer (raw x for layer 0)
    float* cur = bufA;
    for (int i = 0; i < 3; ++i) {
        if (i == 0) {
            k_aggbn<false><<<aggGrid, 256, 0, stream>>>((const float4*)prev_h, rowptr, col,
                                                        nullptr, nullptr, nullptr,
                                                        (float4*)cur, nNodes, invN);
        } else {
            k_aggbn<true><<<aggGrid, 256, 0, stream>>>((const float4*)prev_h, rowptr, col,
                                                       stats + (size_t)(i - 1) * 128,
                                                       gamma + (size_t)(i - 1) * 64,
                                                       beta + (size_t)(i - 1) * 64,
                                                       (float4*)cur, nNodes, invN);
        }
        k_mlp<<<mlpGrid, 256, 0, stream>>>((const float4*)cur, (float4*)cur,
                                           (const float4*)(W1 + (size_t)i * 4096), b1 + (size_t)i * 64,
                                           (const float4*)(W2 + (size_t)i * 4096), b2 + (size_t)i * 64,
                                           stats + (size_t)i * 128, nNodes);
        prev_h = cur;
        cur = (cur == bufA) ? bufB : bufA;
    }

    k_pool<<<64, 256, 0, stream>>>((const float4*)prev_h, batch,
                                   stats + 256, gamma + 128, beta + 128,
                                   Wf, bf, (float*)d_out, nNodes, invN);
}

// Round 5
// 334.599 us; speedup vs baseline: 2.1835x; 1.1498x over previous
//
#include <hip/hip_runtime.h>

#define HIDDEN_C 64

__device__ __forceinline__ float4 f4zero() { return make_float4(0.f, 0.f, 0.f, 0.f); }

#define SWZ(node) ((((node) >> 2) & 7) << 4)

// ---------------- CSR build ----------------
__global__ __launch_bounds__(256) void k_hist(const int* __restrict__ dst,
                                              int* __restrict__ deg, int nE) {
    int i = blockIdx.x * 256 + threadIdx.x;
    if (i < nE) atomicAdd(&deg[dst[i]], 1);
}

__global__ __launch_bounds__(256) void k_blocksum(const int* __restrict__ deg,
                                                  int* __restrict__ partial, int nNodes) {
    int base = blockIdx.x * 1024 + threadIdx.x * 4;
    int s = 0;
#pragma unroll
    for (int k = 0; k < 4; ++k) {
        int i = base + k;
        if (i < nNodes) s += deg[i];
    }
    __shared__ int red[256];
    red[threadIdx.x] = s;
    __syncthreads();
    for (int d = 128; d > 0; d >>= 1) {
        if (threadIdx.x < d) red[threadIdx.x] += red[threadIdx.x + d];
        __syncthreads();
    }
    if (threadIdx.x == 0) partial[blockIdx.x] = red[0];
}

__global__ __launch_bounds__(256) void k_scanpartial(int* __restrict__ partial,
                                                     int* __restrict__ rowptr_last,
                                                     int nBlocks, int nE) {
    __shared__ int buf[256];
    int tid = threadIdx.x;
    int v = (tid < nBlocks) ? partial[tid] : 0;
    buf[tid] = v;
    __syncthreads();
    for (int d = 1; d < 256; d <<= 1) {
        int t = (tid >= d) ? buf[tid - d] : 0;
        __syncthreads();
        buf[tid] += t;
        __syncthreads();
    }
    if (tid < nBlocks) partial[tid] = buf[tid] - v;
    if (tid == 0) rowptr_last[0] = nE;
}

__global__ __launch_bounds__(256) void k_writeptr(const int* __restrict__ deg,
                                                  const int* __restrict__ partial,
                                                  int* __restrict__ rowptr,
                                                  int* __restrict__ cursor, int nNodes) {
    int tid = threadIdx.x;
    int base = blockIdx.x * 1024 + tid * 4;
    int d[4];
    int s = 0;
#pragma unroll
    for (int k = 0; k < 4; ++k) {
        int i = base + k;
        d[k] = (i < nNodes) ? deg[i] : 0;
        s += d[k];
    }
    __shared__ int buf[256];
    buf[tid] = s;
    __syncthreads();
    for (int dd = 1; dd < 256; dd <<= 1) {
        int t = (tid >= dd) ? buf[tid - dd] : 0;
        __syncthreads();
        buf[tid] += t;
        __syncthreads();
    }
    int off = partial[blockIdx.x] + buf[tid] - s;
#pragma unroll
    for (int k = 0; k < 4; ++k) {
        int i = base + k;
        if (i < nNodes) {
            rowptr[i] = off;
            cursor[i] = off;
            off += d[k];
        }
    }
}

__global__ __launch_bounds__(256) void k_fill(const int* __restrict__ src,
                                              const int* __restrict__ dst,
                                              int* __restrict__ cursor,
                                              int* __restrict__ col, int nE) {
    int i = blockIdx.x * 256 + threadIdx.x;
    if (i < nE) {
        int d = dst[i];
        int pos = atomicAdd(&cursor[d], 1);
        col[pos] = src[i];
    }
}

// ---------------- fused BN(prev layer) + gather aggregation ----------------
template <bool DOBN>
__global__ __launch_bounds__(256) void k_aggbn(const float4* __restrict__ x4,
                                               const int* __restrict__ rowptr,
                                               const int* __restrict__ col,
                                               const float* __restrict__ stats,
                                               const float* __restrict__ gamma,
                                               const float* __restrict__ beta,
                                               float4* __restrict__ h4,
                                               int nNodes, float invN) {
    int wid = threadIdx.x >> 6;
    int lane = threadIdx.x & 63;
    int grp = lane >> 4;
    int l16 = lane & 15;
    int n = blockIdx.x * 4 + wid;
    if (n >= nNodes) return;

    float4 sc = make_float4(1.f, 1.f, 1.f, 1.f);
    float4 sh = f4zero();
    if (DOBN) {
        float4 s  = ((const float4*)stats)[l16];
        float4 q  = ((const float4*)stats)[16 + l16];
        float4 ga = ((const float4*)gamma)[l16];
        float4 be = ((const float4*)beta)[l16];
        float m;
        m = s.x * invN; sc.x = ga.x * rsqrtf(q.x * invN - m * m + 1e-5f); sh.x = be.x - m * sc.x;
        m = s.y * invN; sc.y = ga.y * rsqrtf(q.y * invN - m * m + 1e-5f); sh.y = be.y - m * sc.y;
        m = s.z * invN; sc.z = ga.z * rsqrtf(q.z * invN - m * m + 1e-5f); sh.z = be.z - m * sc.z;
        m = s.w * invN; sc.w = ga.w * rsqrtf(q.w * invN - m * m + 1e-5f); sh.w = be.w - m * sc.w;
    }

    float4 acc = f4zero();
    {
        float4 v = x4[(size_t)n * 16 + l16];
        if (DOBN) {
            v.x = fmaxf(fmaf(v.x, sc.x, sh.x), 0.f);
            v.y = fmaxf(fmaf(v.y, sc.y, sh.y), 0.f);
            v.z = fmaxf(fmaf(v.z, sc.z, sh.z), 0.f);
            v.w = fmaxf(fmaf(v.w, sc.w, sh.w), 0.f);
        }
        if (grp == 0) acc = v;
    }

    int lo = rowptr[n], hi = rowptr[n + 1];
    for (int e = lo; e < hi; e += 4) {
        int ee = e + grp;
        bool ok = ee < hi;
        int idx = col[ok ? ee : (hi - 1)];
        float4 v = x4[(size_t)idx * 16 + l16];
        if (DOBN) {
            v.x = fmaxf(fmaf(v.x, sc.x, sh.x), 0.f);
            v.y = fmaxf(fmaf(v.y, sc.y, sh.y), 0.f);
            v.z = fmaxf(fmaf(v.z, sc.z, sh.z), 0.f);
            v.w = fmaxf(fmaf(v.w, sc.w, sh.w), 0.f);
        }
        if (ok) {
            acc.x += v.x; acc.y += v.y; acc.z += v.z; acc.w += v.w;
        }
    }

    acc.x += __shfl_xor(acc.x, 16, 64); acc.y += __shfl_xor(acc.y, 16, 64);
    acc.z += __shfl_xor(acc.z, 16, 64); acc.w += __shfl_xor(acc.w, 16, 64);
    acc.x += __shfl_xor(acc.x, 32, 64); acc.y += __shfl_xor(acc.y, 32, 64);
    acc.z += __shfl_xor(acc.z, 32, 64); acc.w += __shfl_xor(acc.w, 32, 64);

    if (lane < 16) h4[(size_t)n * 16 + l16] = acc;
}

// ---------------- fused 2-layer MLP + BN-stats (b128 LDS, swizzled) ----------------
#define KSTEP(AC, WV)                                                       \
    acc00 = fmaf(a0.AC, WV.x, acc00); acc01 = fmaf(a0.AC, WV.y, acc01);     \
    acc02 = fmaf(a0.AC, WV.z, acc02); acc03 = fmaf(a0.AC, WV.w, acc03);     \
    acc10 = fmaf(a1.AC, WV.x, acc10); acc11 = fmaf(a1.AC, WV.y, acc11);     \
    acc12 = fmaf(a1.AC, WV.z, acc12); acc13 = fmaf(a1.AC, WV.w, acc13);     \
    acc20 = fmaf(a2.AC, WV.x, acc20); acc21 = fmaf(a2.AC, WV.y, acc21);     \
    acc22 = fmaf(a2.AC, WV.z, acc22); acc23 = fmaf(a2.AC, WV.w, acc23);     \
    acc30 = fmaf(a3.AC, WV.x, acc30); acc31 = fmaf(a3.AC, WV.y, acc31);     \
    acc32 = fmaf(a3.AC, WV.z, acc32); acc33 = fmaf(a3.AC, WV.w, acc33);

// unroll 4 (not 16): limits in-flight b128 loads so VGPR stays under the
// launch_bounds(256,4) cap of 128 — round-4's full unroll hit 256 VGPR / 8.5% occ.
#define GEMM_LOOP(SRC)                                                                     \
    _Pragma("unroll 4")                                                                    \
    for (int kb = 0; kb < 16; ++kb) {                                                      \
        int kB = kb * 16;                                                                  \
        float4 a0 = *(const float4*)((const char*)SRC + (nr + 0) * 256 + (kB ^ SWZ(nr + 0))); \
        float4 a1 = *(const float4*)((const char*)SRC + (nr + 1) * 256 + (kB ^ SWZ(nr + 1))); \
        float4 a2 = *(const float4*)((const char*)SRC + (nr + 2) * 256 + (kB ^ SWZ(nr + 2))); \
        float4 a3 = *(const float4*)((const char*)SRC + (nr + 3) * 256 + (kB ^ SWZ(nr + 3))); \
        const char* wrow = (const char*)sW + kb * 1024 + fc * 4;                           \
        float4 w0 = *(const float4*)(wrow);                                               \
        float4 w1 = *(const float4*)(wrow + 256);                                         \
        float4 w2 = *(const float4*)(wrow + 512);                                         \
        float4 w3 = *(const float4*)(wrow + 768);                                         \
        KSTEP(x, w0) KSTEP(y, w1) KSTEP(z, w2) KSTEP(w, w3)                                \
    }

__global__ __launch_bounds__(256, 4) void k_mlp(const float4* __restrict__ h_in4,
                                                float4* __restrict__ h_out4,
                                                const float4* __restrict__ W1_4,
                                                const float* __restrict__ b1,
                                                const float4* __restrict__ W2_4,
                                                const float* __restrict__ b2,
                                                float* __restrict__ stats,
                                                int nNodes) {
    __shared__ float sA[4096];
    __shared__ float sW[4096];
    __shared__ float sH1[4096];

    int tid = threadIdx.x;
    int n0 = blockIdx.x * 64;
    int nr = (tid >> 4) * 4;
    int fc = (tid & 15) * 4;

#pragma unroll
    for (int it = 0; it < 4; ++it) {
        int i = it * 256 + tid;
        ((float4*)sW)[i] = W1_4[i];
        int node = i >> 4, slot = i & 15;
        float4 v = (n0 + node < nNodes) ? h_in4[(size_t)(n0 + node) * 16 + slot] : f4zero();
        *(float4*)((char*)sA + node * 256 + ((slot * 16) ^ SWZ(node))) = v;
    }
    __syncthreads();

    float4 bias = ((const float4*)b1)[tid & 15];
    float acc00 = bias.x, acc01 = bias.y, acc02 = bias.z, acc03 = bias.w;
    float acc10 = bias.x, acc11 = bias.y, acc12 = bias.z, acc13 = bias.w;
    float acc20 = bias.x, acc21 = bias.y, acc22 = bias.z, acc23 = bias.w;
    float acc30 = bias.x, acc31 = bias.y, acc32 = bias.z, acc33 = bias.w;

    GEMM_LOOP(sA)

    {
        float4 r;
        r.x = fmaxf(acc00, 0.f); r.y = fmaxf(acc01, 0.f); r.z = fmaxf(acc02, 0.f); r.w = fmaxf(acc03, 0.f);
        *(float4*)((char*)sH1 + (nr + 0) * 256 + ((fc * 4) ^ SWZ(nr + 0))) = r;
        r.x = fmaxf(acc10, 0.f); r.y = fmaxf(acc11, 0.f); r.z = fmaxf(acc12, 0.f); r.w = fmaxf(acc13, 0.f);
        *(float4*)((char*)sH1 + (nr + 1) * 256 + ((fc * 4) ^ SWZ(nr + 1))) = r;
        r.x = fmaxf(acc20, 0.f); r.y = fmaxf(acc21, 0.f); r.z = fmaxf(acc22, 0.f); r.w = fmaxf(acc23, 0.f);
        *(float4*)((char*)sH1 + (nr + 2) * 256 + ((fc * 4) ^ SWZ(nr + 2))) = r;
        r.x = fmaxf(acc30, 0.f); r.y = fmaxf(acc31, 0.f); r.z = fmaxf(acc32, 0.f); r.w = fmaxf(acc33, 0.f);
        *(float4*)((char*)sH1 + (nr + 3) * 256 + ((fc * 4) ^ SWZ(nr + 3))) = r;
    }

    __syncthreads();
#pragma unroll
    for (int it = 0; it < 4; ++it) {
        int i = it * 256 + tid;
        ((float4*)sW)[i] = W2_4[i];
    }
    __syncthreads();

    bias = ((const float4*)b2)[tid & 15];
    acc00 = bias.x; acc01 = bias.y; acc02 = bias.z; acc03 = bias.w;
    acc10 = bias.x; acc11 = bias.y; acc12 = bias.z; acc13 = bias.w;
    acc20 = bias.x; acc21 = bias.y; acc22 = bias.z; acc23 = bias.w;
    acc30 = bias.x; acc31 = bias.y; acc32 = bias.z; acc33 = bias.w;

    GEMM_LOOP(sH1)

    // epilogue: relu, store, per-feature partial stats
    float sj0 = 0.f, sj1 = 0.f, sj2 = 0.f, sj3 = 0.f;
    float qj0 = 0.f, qj1 = 0.f, qj2 = 0.f, qj3 = 0.f;
    {
        int node = n0 + nr;
        float4 r;
        if (node + 0 < nNodes) {
            r.x = fmaxf(acc00, 0.f); r.y = fmaxf(acc01, 0.f); r.z = fmaxf(acc02, 0.f); r.w = fmaxf(acc03, 0.f);
            h_out4[(size_t)(node + 0) * 16 + (fc >> 2)] = r;
            sj0 += r.x; qj0 += r.x * r.x; sj1 += r.y; qj1 += r.y * r.y;
            sj2 += r.z; qj2 += r.z * r.z; sj3 += r.w; qj3 += r.w * r.w;
        }
        if (node + 1 < nNodes) {
            r.x = fmaxf(acc10, 0.f); r.y = fmaxf(acc11, 0.f); r.z = fmaxf(acc12, 0.f); r.w = fmaxf(acc13, 0.f);
            h_out4[(size_t)(node + 1) * 16 + (fc >> 2)] = r;
            sj0 += r.x; qj0 += r.x * r.x; sj1 += r.y; qj1 += r.y * r.y;
            sj2 += r.z; qj2 += r.z * r.z; sj3 += r.w; qj3 += r.w * r.w;
        }
        if (node + 2 < nNodes) {
            r.x = fmaxf(acc20, 0.f); r.y = fmaxf(acc21, 0.f); r.z = fmaxf(acc22, 0.f); r.w = fmaxf(acc23, 0.f);
            h_out4[(size_t)(node + 2) * 16 + (fc >> 2)] = r;
            sj0 += r.x; qj0 += r.x * r.x; sj1 += r.y; qj1 += r.y * r.y;
            sj2 += r.z; qj2 += r.z * r.z; sj3 += r.w; qj3 += r.w * r.w;
        }
        if (node + 3 < nNodes) {
            r.x = fmaxf(acc30, 0.f); r.y = fmaxf(acc31, 0.f); r.z = fmaxf(acc32, 0.f); r.w = fmaxf(acc33, 0.f);
            h_out4[(size_t)(node + 3) * 16 + (fc >> 2)] = r;
            sj0 += r.x; qj0 += r.x * r.x; sj1 += r.y; qj1 += r.y * r.y;
            sj2 += r.z; qj2 += r.z * r.z; sj3 += r.w; qj3 += r.w * r.w;
        }
    }

    float* sS = sA;
    float* sQ = sA + 1024;
    int rrow = tid >> 4;
    sS[rrow * 64 + fc + 0] = sj0; sS[rrow * 64 + fc + 1] = sj1;
    sS[rrow * 64 + fc + 2] = sj2; sS[rrow * 64 + fc + 3] = sj3;
    sQ[rrow * 64 + fc + 0] = qj0; sQ[rrow * 64 + fc + 1] = qj1;
    sQ[rrow * 64 + fc + 2] = qj2; sQ[rrow * 64 + fc + 3] = qj3;
    __syncthreads();
    if (tid < 64) {
        float S = 0.f;
#pragma unroll
        for (int r = 0; r < 16; ++r) S += sS[r * 64 + tid];
        atomicAdd(&stats[tid], S);
    } else if (tid < 128) {
        int f = tid - 64;
        float Q = 0.f;
#pragma unroll
        for (int r = 0; r < 16; ++r) Q += sQ[r * 64 + f];
        atomicAdd(&stats[64 + f], Q);
    }
}

// ---------------- pooling (BN3 fused) + final GEMV ----------------
__device__ __forceinline__ int lower_bound_dev(const int* a, int n, int key) {
    int lo = 0, hi = n;
    while (lo < hi) {
        int mid = (lo + hi) >> 1;
        if (a[mid] < key) lo = mid + 1; else hi = mid;
    }
    return lo;
}

__global__ __launch_bounds__(256) void k_pool(const float4* __restrict__ x4,
                                              const int* __restrict__ batch,
                                              const float* __restrict__ stats,
                                              const float* __restrict__ gamma,
                                              const float* __restrict__ beta,
                                              const float* __restrict__ Wf,
                                              const float* __restrict__ bf,
                                              float* __restrict__ out,
                                              int nNodes, float invN) {
    int wid = threadIdx.x >> 6;
    int lane = threadIdx.x & 63;
    int grp = lane >> 4;
    int l16 = lane & 15;
    int g = blockIdx.x * 4 + wid;

    float4 sc, sh;
    {
        float4 s  = ((const float4*)stats)[l16];
        float4 q  = ((const float4*)stats)[16 + l16];
        float4 ga = ((const float4*)gamma)[l16];
        float4 be = ((const float4*)beta)[l16];
        float m;
        m = s.x * invN; sc.x = ga.x * rsqrtf(q.x * invN - m * m + 1e-5f); sh.x = be.x - m * sc.x;
        m = s.y * invN; sc.y = ga.y * rsqrtf(q.y * invN - m * m + 1e-5f); sh.y = be.y - m * sc.y;
        m = s.z * invN; sc.z = ga.z * rsqrtf(q.z * invN - m * m + 1e-5f); sh.z = be.z - m * sc.z;
        m = s.w * invN; sc.w = ga.w * rsqrtf(q.w * invN - m * m + 1e-5f); sh.w = be.w - m * sc.w;
    }

    int lo = lower_bound_dev(batch, nNodes, g);
    int hi = lower_bound_dev(batch, nNodes, g + 1);

    float4 acc = f4zero();
    for (int r = lo + grp; r < hi; r += 4) {
        float4 v = x4[(size_t)r * 16 + l16];
        acc.x += fmaxf(fmaf(v.x, sc.x, sh.x), 0.f);
        acc.y += fmaxf(fmaf(v.y, sc.y, sh.y), 0.f);
        acc.z += fmaxf(fmaf(v.z, sc.z, sh.z), 0.f);
        acc.w += fmaxf(fmaf(v.w, sc.w, sh.w), 0.f);
    }
    acc.x += __shfl_xor(acc.x, 16, 64); acc.y += __shfl_xor(acc.y, 16, 64);
    acc.z += __shfl_xor(acc.z, 16, 64); acc.w += __shfl_xor(acc.w, 16, 64);
    acc.x += __shfl_xor(acc.x, 32, 64); acc.y += __shfl_xor(acc.y, 32, 64);
    acc.z += __shfl_xor(acc.z, 32, 64); acc.w += __shfl_xor(acc.w, 32, 64);

    float4 wf = ((const float4*)Wf)[l16];
    float p = acc.x * wf.x + acc.y * wf.y + acc.z * wf.z + acc.w * wf.w;
    p += __shfl_xor(p, 1, 64);
    p += __shfl_xor(p, 2, 64);
    p += __shfl_xor(p, 4, 64);
    p += __shfl_xor(p, 8, 64);
    if (lane == 0) out[g] = p + bf[0];
}

extern "C" void kernel_launch(void* const* d_in, const int* in_sizes, int n_in,
                              void* d_out, int out_size, void* d_ws, size_t ws_size,
                              hipStream_t stream) {
    const float* x_in  = (const float*)d_in[0];
    const int*   ei    = (const int*)d_in[1];
    const int*   batch = (const int*)d_in[2];
    const float* W1    = (const float*)d_in[3];
    const float* b1    = (const float*)d_in[4];
    const float* W2    = (const float*)d_in[5];
    const float* b2    = (const float*)d_in[6];
    const float* gamma = (const float*)d_in[7];
    const float* beta  = (const float*)d_in[8];
    const float* Wf    = (const float*)d_in[9];
    const float* bf    = (const float*)d_in[10];

    const int nNodes = in_sizes[0] / HIDDEN_C;   // 50000
    const int nE = in_sizes[1] / 2;              // 800000
    const int* src = ei;
    const int* dst = ei + nE;

    const size_t NB = (size_t)nNodes * HIDDEN_C * sizeof(float);  // 12.8 MB
    char* ws = (char*)d_ws;
    float* bufA    = (float*)ws;
    float* bufB    = (float*)(ws + NB);
    float* stats   = (float*)(ws + 2 * NB);           // 3 x 128 floats
    int*   deg     = (int*)(ws + 2 * NB + 4096);      // nNodes ints (aliases cursor)
    int*   rowptr  = deg + nNodes;                    // nNodes+1 ints
    int*   partial = rowptr + nNodes + 1;             // 256 ints
    int*   col     = partial + 256;                   // nE ints

    const int mlpGrid = (nNodes + 63) / 64;
    const int edgeGrid = (nE + 255) / 256;
    const int aggGrid = (nNodes + 3) / 4;
    const int scanBlocks = (nNodes + 1023) / 1024;
    const float invN = 1.f / (float)nNodes;

    hipMemsetAsync(stats, 0, 384 * sizeof(float), stream);
    hipMemsetAsync(deg, 0, (size_t)nNodes * sizeof(int), stream);
    k_hist<<<edgeGrid, 256, 0, stream>>>(dst, deg, nE);
    k_blocksum<<<scanBlocks, 256, 0, stream>>>(deg, partial, nNodes);
    k_scanpartial<<<1, 256, 0, stream>>>(partial, rowptr + nNodes, scanBlocks, nE);
    k_writeptr<<<scanBlocks, 256, 0, stream>>>(deg, partial, rowptr, deg, nNodes);
    k_fill<<<edgeGrid, 256, 0, stream>>>(src, dst, deg, col, nE);

    const float* prev_h = x_in;
    float* cur = bufA;
    for (int i = 0; i < 3; ++i) {
        if (i == 0) {
            k_aggbn<false><<<aggGrid, 256, 0, stream>>>((const float4*)prev_h, rowptr, col,
                                                        nullptr, nullptr, nullptr,
                                                        (float4*)cur, nNodes, invN);
        } else {
            k_aggbn<true><<<aggGrid, 256, 0, stream>>>((const float4*)prev_h, rowptr, col,
                                                       stats + (size_t)(i - 1) * 128,
                                                       gamma + (size_t)(i - 1) * 64,
                                                       beta + (size_t)(i - 1) * 64,
                                                       (float4*)cur, nNodes, invN);
        }
        k_mlp<<<mlpGrid, 256, 0, stream>>>((const float4*)cur, (float4*)cur,
                                           (const float4*)(W1 + (size_t)i * 4096), b1 + (size_t)i * 64,
                                           (const float4*)(W2 + (size_t)i * 4096), b2 + (size_t)i * 64,
                                           stats + (size_t)i * 128, nNodes);
        prev_h = cur;
        cur = (cur == bufA) ? bufB : bufA;
    }

    k_pool<<<64, 256, 0, stream>>>((const float4*)prev_h, batch,
                                   stats + 256, gamma + 128, beta + 128,
                                   Wf, bf, (float*)d_out, nNodes, invN);
}